// Round 8
// baseline (454.711 us; speedup 1.0000x reference)
//
#include <hip/hip_runtime.h>
#include <hip/hip_bf16.h>

typedef __attribute__((ext_vector_type(8)))  short          bf16x8;
typedef __attribute__((ext_vector_type(16))) float          f32x16;
typedef __attribute__((ext_vector_type(8)))  unsigned short u16x8;

#define N_EMB 200000
#define K_C   512
#define D_DIM 128
#define TPB   10            // tiles per block; 6250 = 625 x 10 exact
#define NGRPS 625
#define AROW  144           // hiA row: 128 data + 8 fold + 8 zero
#define SLOTB 17408         // LDS slot: 16 KB data + 1 KB fold group
#define MINOFF (3 * SLOTB)  // 52224

// ws layout (bytes):
//   0        pack u64[512]          (4096)
//   4096     hiA u16[512*144]       (147456) -> 151552
//   151552   loA u16[512*128]       (131072) -> 282624
//   282624   foldg u16[6250*512]    (6400000)-> 6682624
//   6682624  minA u32[200000]       (800000) -> 7482624
//   7482624  minB u32[200000]       (800000) -> 8282624
//   8282624  lossPartial f32[391]

__device__ __forceinline__ unsigned short bf16_bits(float x) {
    __hip_bfloat16 h = __float2bfloat16(x);
    return *reinterpret_cast<unsigned short*>(&h);
}
__device__ __forceinline__ float bf16_val(unsigned short b) {
    unsigned u = (unsigned)b << 16;
    return __uint_as_float(u);
}
__device__ __forceinline__ void gload_lds16(const void* g, void* l) {
    __builtin_amdgcn_global_load_lds(
        (const __attribute__((address_space(1))) unsigned int*)g,
        (__attribute__((address_space(3))) unsigned int*)l, 16, 0, 0);
}

// ---- pre-pass: convert embs -> tile layout [g][hl][n][16B] IN PLACE (16 KB/tile),
//      fold group {1,1,1,x2h,x2l,e2x,0,0} -> foldg (1 KB/tile). All global r/w coalesced
//      via LDS transpose. Blocks 0..63 additionally do the A-side prep (merged init).
__global__ void prep_b(float* __restrict__ embs_rw,
                       const float* __restrict__ centers,
                       unsigned short* __restrict__ foldg,
                       unsigned short* __restrict__ hiA,
                       unsigned short* __restrict__ loA,
                       unsigned long long* __restrict__ pack) {
    __shared__ __align__(16) unsigned short lds[2 * 32 * 136 + 32 * 8];
    unsigned short* hiP = lds;                 // [32][136] padded rows (272 B, 16B-mult)
    unsigned short* loP = lds + 32 * 136;
    unsigned short* x2P = lds + 2 * 32 * 136;  // [32][8] prebuilt fold rows

    const int T = blockIdx.x, t = threadIdx.x;
    const int n = t >> 4, g = t & 15;
    float* base = embs_rw + (size_t)T * (32 * D_DIM);

    float4 u0, u1;
    {
        const float* src = base + n * D_DIM + g * 8;   // coalesced: wave = 2 KB contig
        u0 = *reinterpret_cast<const float4*>(src);
        u1 = *reinterpret_cast<const float4*>(src + 4);
    }
    float v[8] = {u0.x, u0.y, u0.z, u0.w, u1.x, u1.y, u1.z, u1.w};
    float x2p = 0.f;
    u16x8 hv, lv;
#pragma unroll
    for (int i = 0; i < 8; ++i) {
        x2p = fmaf(v[i], v[i], x2p);
        unsigned short hb = bf16_bits(v[i]);
        unsigned short lb = bf16_bits(v[i] - bf16_val(hb));
        hv[i] = hb; lv[i] = lb;
    }
    *reinterpret_cast<u16x8*>(hiP + n * 136 + 8 * g) = hv;
    *reinterpret_cast<u16x8*>(loP + n * 136 + 8 * g) = lv;
    float x2 = x2p;
#pragma unroll
    for (int off = 1; off < 16; off <<= 1) x2 += __shfl_xor(x2, off);
    if (g == 0) {
        unsigned short x2h = bf16_bits(x2);
        float x2hf = bf16_val(x2h);
        unsigned short x2l = bf16_bits(x2 - x2hf);
        float x2lf = bf16_val(x2l);
        unsigned short e2x = bf16_bits(x2 - x2hf - x2lf);
        u16x8 f;
        f[0] = 0x3F80; f[1] = 0x3F80; f[2] = 0x3F80;
        f[3] = x2h; f[4] = x2l; f[5] = e2x; f[6] = 0; f[7] = 0;
        *reinterpret_cast<u16x8*>(x2P + n * 8) = f;
    }
    __syncthreads();

    // coalesced stores: data chunks c=0..1023 in place, fold chunks -> foldg
    unsigned short* ob = reinterpret_cast<unsigned short*>(base);
#pragma unroll
    for (int cc = 0; cc < 2; ++cc) {
        const int c = t + cc * 512;
        const int g2 = c >> 6, hl = (c >> 5) & 1, n2 = c & 31;
        const unsigned short* pl = hl ? loP : hiP;
        u16x8 val = *reinterpret_cast<const u16x8*>(pl + n2 * 136 + 8 * g2);
        *reinterpret_cast<u16x8*>(ob + c * 8) = val;
    }
    if (t < 64) {
        const int hl = t >> 5, n2 = t & 31;
        u16x8 val;
        if (hl == 0) val = *reinterpret_cast<const u16x8*>(x2P + n2 * 8);
        else {
#pragma unroll
            for (int i = 0; i < 8; ++i) val[i] = 0;
        }
        *reinterpret_cast<u16x8*>(foldg + (size_t)T * 512 + t * 8) = val;
    }

    // ---- merged A prep (blocks 0..63) ----
    if (T < 64) {
        const int w = t >> 6, l = t & 63;
        const int k = T * 8 + w;
        const float2 c = *reinterpret_cast<const float2*>(centers + k * D_DIM + 2 * l);
        float c2 = c.x * c.x + c.y * c.y;
#pragma unroll
        for (int off = 1; off < 64; off <<= 1) c2 += __shfl_xor(c2, off);
        float v0 = -2.f * c.x, v1 = -2.f * c.y;
        unsigned short h0 = bf16_bits(v0); unsigned short l0 = bf16_bits(v0 - bf16_val(h0));
        unsigned short h1 = bf16_bits(v1); unsigned short l1 = bf16_bits(v1 - bf16_val(h1));
        *reinterpret_cast<ushort2*>(hiA + k * AROW + 2 * l) = make_ushort2(h0, h1);
        *reinterpret_cast<ushort2*>(loA + k * D_DIM + 2 * l) = make_ushort2(l0, l1);
        if (l == 0) {   // A fold: {c2h, c2l, e2c, 1, 1, 1, 0, 0} then zeros (half1)
            unsigned short c2h = bf16_bits(c2);
            float c2hf = bf16_val(c2h);
            unsigned short c2l = bf16_bits(c2 - c2hf);
            float c2lf = bf16_val(c2l);
            unsigned short e2c = bf16_bits(c2 - c2hf - c2lf);
            u16x8 a, z;
#pragma unroll
            for (int i = 0; i < 8; ++i) { a[i] = 0; z[i] = 0; }
            a[0] = c2h; a[1] = c2l; a[2] = e2c;
            a[3] = 0x3F80; a[4] = 0x3F80; a[5] = 0x3F80;
            *reinterpret_cast<u16x8*>(hiA + k * AROW + 128) = a;
            *reinterpret_cast<u16x8*>(hiA + k * AROW + 136) = z;
        }
        if (l == 1) pack[k] = 0xFFFFFFFFFFFFFFFFULL;
    }
}

__launch_bounds__(512, 4)
__global__ void cluster_mfma(const float* __restrict__ embs_conv,
                             const unsigned short* __restrict__ hiA,
                             const unsigned short* __restrict__ loA,
                             const unsigned short* __restrict__ foldg,
                             unsigned long long* __restrict__ pack,
                             unsigned* __restrict__ minA,
                             unsigned* __restrict__ minB) {
    __shared__ __align__(16) char lds_c[3 * SLOTB + TPB * 32 * 4];   // 53504 B
    unsigned* minarr = reinterpret_cast<unsigned*>(lds_c + MINOFF);
    const char* hlB = reinterpret_cast<const char*>(embs_conv);
    const char* fB  = reinterpret_cast<const char*>(foldg);

    const int t = threadIdx.x, w = t >> 6, l = t & 63;
    const int col = l & 31, half = l >> 5;
    const int kside = blockIdx.x & 1, ngrp = blockIdx.x >> 1;
    const int kbase = kside * 256 + w * 32;
    const int myk = kbase + col;
    const int tbase = ngrp * TPB;

    bf16x8 a_hi[8], a_lo[8], afold;
    {
        const unsigned short* hrow = hiA + myk * AROW + 8 * half;
        const unsigned short* lrow = loA + myk * D_DIM + 8 * half;
#pragma unroll
        for (int s = 0; s < 8; ++s) {
            a_hi[s] = *reinterpret_cast<const bf16x8*>(hrow + 16 * s);
            a_lo[s] = *reinterpret_cast<const bf16x8*>(lrow + 16 * s);
        }
        afold = *reinterpret_cast<const bf16x8*>(hiA + myk * AROW + 128 + 8 * half);
    }

    float best_d[16];
#pragma unroll
    for (int r = 0; r < 16; ++r) best_d[r] = 3.4e38f;
    unsigned nib0 = 0u, nib1 = 0u;
    if (t < TPB * 32) minarr[t] = 0xFFFFFFFFu;

    // DMA: 16 KB data (2 issues/wave) + 1 KB fold (wave 0 only)
#define ISSUE(TL) do {                                                          \
        char* dst_ = lds_c + ((TL) % 3) * SLOTB;                                \
        const char* src_ = hlB + (size_t)(tbase + (TL)) * 16384;                \
        gload_lds16(src_ + ((w * 2 + 0) << 10) + (l << 4),                      \
                    dst_ + ((w * 2 + 0) << 10) + (l << 4));                     \
        gload_lds16(src_ + ((w * 2 + 1) << 10) + (l << 4),                      \
                    dst_ + ((w * 2 + 1) << 10) + (l << 4));                     \
        if (w == 0)                                                             \
            gload_lds16(fB + (size_t)(tbase + (TL)) * 1024 + (l << 4),          \
                        dst_ + 16384 + (l << 4));                               \
    } while (0)

    ISSUE(0);
    ISSUE(1);

#pragma unroll
    for (int tl = 0; tl < TPB; ++tl) {
        char* buf = lds_c + (tl % 3) * SLOTB;

        // drain THIS tile's DMAs only; next tile's stay in flight (counted vmcnt)
        if (tl == TPB - 1)      asm volatile("s_waitcnt vmcnt(0)" ::: "memory");
        else if (w == 0)        asm volatile("s_waitcnt vmcnt(3)" ::: "memory");
        else                    asm volatile("s_waitcnt vmcnt(2)" ::: "memory");
        __builtin_amdgcn_s_barrier();
        // issue prefetch AFTER barrier: barrier(t+1) protects reads(t) from the
        // DMA issued at t+1 into the slot read at t (ring of 3, distance 2).
        if (tl < TPB - 2) ISSUE(tl + 2);

        f32x16 acc;
#pragma unroll
        for (int r = 0; r < 16; ++r) acc[r] = 0.f;
#pragma unroll
        for (int s = 0; s < 8; ++s) {
            const char* pb = buf + ((2 * s + half) << 10) + (col << 4);
            bf16x8 bh = *reinterpret_cast<const bf16x8*>(pb);
            bf16x8 bl = *reinterpret_cast<const bf16x8*>(pb + 512);
            acc = __builtin_amdgcn_mfma_f32_32x32x16_bf16(a_hi[s], bh, acc, 0, 0, 0);
            acc = __builtin_amdgcn_mfma_f32_32x32x16_bf16(a_hi[s], bl, acc, 0, 0, 0);
            acc = __builtin_amdgcn_mfma_f32_32x32x16_bf16(a_lo[s], bh, acc, 0, 0, 0);
        }
        {   // fold MFMA: adds c2[k] + x2[n]  ->  acc IS d2
            bf16x8 bf = *reinterpret_cast<const bf16x8*>(
                buf + 16384 + (half << 9) + (col << 4));
            acc = __builtin_amdgcn_mfma_f32_32x32x16_bf16(afold, bf, acc, 0, 0, 0);
        }

        // loss: min over this wave's 32 k for col
        float m = acc[0];
#pragma unroll
        for (int r = 1; r < 16; ++r) m = fminf(m, acc[r]);
        m = fminf(m, __shfl_xor(m, 32));
        if (l < 32) atomicMin(&minarr[tl * 32 + col], __float_as_uint(m));

        // rep: per-(lane,reg) running best, 4-bit tile index
        const unsigned tlu = (unsigned)tl;
#pragma unroll
        for (int r = 0; r < 16; ++r) {
            const bool better = acc[r] < best_d[r];
            best_d[r] = better ? acc[r] : best_d[r];
            const int sh = 4 * (r & 7);
            if (r < 8) nib0 = better ? ((nib0 & ~(0xFu << sh)) | (tlu << sh)) : nib0;
            else       nib1 = better ? ((nib1 & ~(0xFu << sh)) | (tlu << sh)) : nib1;
        }
    }
    __syncthreads();

    if (t < TPB * 32) {
        unsigned* dst = kside ? minB : minA;
        dst[ngrp * (TPB * 32) + t] = minarr[t];
    }

#pragma unroll
    for (int r = 0; r < 16; ++r) {
        float d = best_d[r];
        const unsigned nib = ((r < 8 ? nib0 : nib1) >> (4 * (r & 7))) & 0xFu;
        unsigned n = (unsigned)((tbase + (int)nib) * 32 + col);
        for (int off = 16; off >= 1; off >>= 1) {
            float od = __shfl_xor(d, off);
            unsigned on = __shfl_xor(n, off);
            bool take = (od < d) || (od == d && on < n);
            d = take ? od : d;
            n = take ? on : n;
        }
        if (col == 0) {
            int k = kbase + (r & 3) + 8 * (r >> 2) + 4 * half;
            unsigned long long p =
                ((unsigned long long)__float_as_uint(d + 1024.f) << 32) |
                (unsigned long long)n;
            atomicMin(&pack[k], p);
        }
    }
}

__global__ void finalize1(const float* __restrict__ centers,
                          const unsigned long long* __restrict__ pack,
                          const unsigned* __restrict__ minA,
                          const unsigned* __restrict__ minB,
                          float* __restrict__ lossPartial,
                          float* __restrict__ out) {
    __shared__ float wsum[8];
    const int t = threadIdx.x, wv = t >> 6, ln = t & 63;
    const int gid = blockIdx.x * 512 + t;
    if (gid < 16384)
        reinterpret_cast<float4*>(out)[gid] =
            reinterpret_cast<const float4*>(centers)[gid];
    if (gid < K_C)
        out[65536 + gid] = (float)(unsigned)(pack[gid] & 0xFFFFFFFFu);
    float s = 0.f;
    if (gid < N_EMB) {
        float m = fminf(__uint_as_float(minA[gid]), __uint_as_float(minB[gid]));
        s = sqrtf(fmaxf(m, 1e-12f));
    }
#pragma unroll
    for (int off = 1; off < 64; off <<= 1) s += __shfl_xor(s, off);
    if (ln == 0) wsum[wv] = s;
    __syncthreads();
    if (t == 0) {
        float tot = 0.f;
#pragma unroll
        for (int i = 0; i < 8; ++i) tot += wsum[i];
        lossPartial[blockIdx.x] = tot;   // plain store — no global atomics
    }
}

__global__ void finalize2(const float* __restrict__ lossPartial,
                          float* __restrict__ out) {
    __shared__ float wsum[8];
    const int t = threadIdx.x, wv = t >> 6, ln = t & 63;
    float s = (t < 391) ? lossPartial[t] : 0.f;
#pragma unroll
    for (int off = 1; off < 64; off <<= 1) s += __shfl_xor(s, off);
    if (ln == 0) wsum[wv] = s;
    __syncthreads();
    if (t == 0) {
        float tot = 0.f;
#pragma unroll
        for (int i = 0; i < 8; ++i) tot += wsum[i];
        out[65536 + K_C] = tot;
    }
}

extern "C" void kernel_launch(void* const* d_in, const int* in_sizes, int n_in,
                              void* d_out, int out_size, void* d_ws, size_t ws_size,
                              hipStream_t stream) {
    float* embs_rw       = (float*)d_in[0];          // converted in place each launch
    const float* centers = (const float*)d_in[1];
    float* out = (float*)d_out;

    unsigned long long* pack = (unsigned long long*)d_ws;
    unsigned short* hiA = (unsigned short*)((char*)d_ws + 4096);
    unsigned short* loA = (unsigned short*)((char*)d_ws + 151552);
    unsigned short* foldg = (unsigned short*)((char*)d_ws + 282624);
    unsigned* minA = (unsigned*)((char*)d_ws + 6682624);
    unsigned* minB = (unsigned*)((char*)d_ws + 7482624);
    float* lossPartial = (float*)((char*)d_ws + 8282624);

    prep_b<<<6250, 512, 0, stream>>>(embs_rw, centers, foldg, hiA, loA, pack);
    cluster_mfma<<<NGRPS * 2, 512, 0, stream>>>((const float*)embs_rw, hiA, loA,
                                                foldg, pack, minA, minB);
    finalize1<<<391, 512, 0, stream>>>(centers, pack, minA, minB, lossPartial, out);
    finalize2<<<1, 512, 0, stream>>>(lossPartial, out);
}